// Round 1
// 193.002 us; speedup vs baseline: 1.0247x; 1.0247x over previous
//
#include <hip/hip_runtime.h>

typedef __bf16 bf16_t;
typedef __bf16 bf16x2 __attribute__((ext_vector_type(2)));
typedef __bf16 bf16x4 __attribute__((ext_vector_type(4)));
typedef __bf16 bf16x8 __attribute__((ext_vector_type(8)));
typedef float f32x4 __attribute__((ext_vector_type(4)));
typedef unsigned u32;
typedef unsigned u32x4 __attribute__((ext_vector_type(4)));

#define N_PIX 4096
#define CFEAT 256
#define CKEY 32
#define NBATCH 4

#if __has_builtin(__builtin_amdgcn_exp2f)
#define EXP2(x) __builtin_amdgcn_exp2f(x)
#else
#define EXP2(x) exp2f(x)
#endif

static __device__ __forceinline__ f32x4 mfma16(bf16x8 a, bf16x8 b, f32x4 c) {
    return __builtin_amdgcn_mfma_f32_16x16x32_bf16(a, b, c, 0, 0, 0);
}

// async global->LDS, 16B per lane; LDS dest = wave-uniform base + lane*16
static __device__ __forceinline__ void glds16(const void* g, void* l) {
    __builtin_amdgcn_global_load_lds(
        (const __attribute__((address_space(1))) void*)g,
        (__attribute__((address_space(3))) void*)l, 16, 0, 0);
}

// pack two f32 -> one dword of 2 bf16 (compiler emits v_cvt_pk_bf16_f32)
static __device__ __forceinline__ u32 pk2(float lo, float hi) {
    bf16x2 t; t[0] = (bf16_t)lo; t[1] = (bf16_t)hi;
    return __builtin_bit_cast(u32, t);
}

// 4-group transpose step (T12): on entry x,y live in all 4 lane-groups.
// On exit: x = (x@g0, x@g2, y@g0, y@g2), y = (x@g1, x@g3, y@g1, y@g3)
// (values per lane-group, same ln within group).
static __device__ __forceinline__ void xpose4(u32 &x, u32 &y) {
#if __has_builtin(__builtin_amdgcn_permlane32_swap) && __has_builtin(__builtin_amdgcn_permlane16_swap)
    auto r32 = __builtin_amdgcn_permlane32_swap(x, y, false, false);
    auto r16 = __builtin_amdgcn_permlane16_swap(r32[0], r32[1], false, false);
    x = r16[0]; y = r16[1];
#else
    const int lane = threadIdx.x & 63;
    const int g = lane >> 4, ln = lane & 15;
    const int i0 = ln + ((g & 1) << 5);
    const int i2 = i0 + 16;
    u32 xs0 = (u32)__shfl((int)x, i0), ys0 = (u32)__shfl((int)y, i0);
    u32 xs2 = (u32)__shfl((int)x, i2), ys2 = (u32)__shfl((int)y, i2);
    x = (g < 2) ? xs0 : ys0;
    y = (g < 2) ? xs2 : ys2;
#endif
}

// S^T tile (64 j x 16 i) -> exp -> in-register P fragments for the PV MFMAs.
// pa0: B[k=g*8+e][col=ln] = P[j=k][i=ln], pa1: same for j = 32+k.
static __device__ __forceinline__ void softmax_tile(
    const bf16x8 kf[4], bf16x8 qf, bool addl,
    float &ls0, float &ls1, float &ls2, float &ls3,
    bf16x8 &pa0, bf16x8 &pa1)
{
    f32x4 zero = {0.f, 0.f, 0.f, 0.f};
    f32x4 st[4];
#pragma unroll
    for (int jt = 0; jt < 4; ++jt) st[jt] = mfma16(kf[jt], qf, zero);
    float ex[16];
#pragma unroll
    for (int jt = 0; jt < 4; ++jt)
#pragma unroll
        for (int r = 0; r < 4; ++r) ex[jt * 4 + r] = EXP2(st[jt][r]);
    if (addl) {
#pragma unroll
        for (int t = 0; t < 16; t += 4) {
            ls0 += ex[t]; ls1 += ex[t + 1]; ls2 += ex[t + 2]; ls3 += ex[t + 3];
        }
    }
    // d[jt][p] = bf16x2 of P rows (jt*16 + g*4 + 2p, +1) at col ln
    u32 a0 = pk2(ex[0],  ex[1]),  a1 = pk2(ex[2],  ex[3]);
    u32 b0 = pk2(ex[4],  ex[5]),  b1 = pk2(ex[6],  ex[7]);
    u32 c0 = pk2(ex[8],  ex[9]),  c1 = pk2(ex[10], ex[11]);
    u32 d0 = pk2(ex[12], ex[13]), d1 = pk2(ex[14], ex[15]);
    xpose4(a0, b0); xpose4(a1, b1);   // -> pa0 dwords {q0,q1,q2,q3} = {a0,a1,b0,b1}
    xpose4(c0, d0); xpose4(c1, d1);   // -> pa1
    u32x4 w0 = {a0, a1, b0, b1};
    u32x4 w1 = {c0, c1, d0, d1};
    pa0 = __builtin_bit_cast(bf16x8, w0);
    pa1 = __builtin_bit_cast(bf16x8, w1);
}

// ---------------------------------------------------------------------------
// projqk: Yt[b][n][32] = bf16(W.X + bias), transposed out. Q side pre-scaled
// by log2(e) so pv's softmax can use raw v_exp_f32 (2^x).
// grid (N/64, 2, B), block 256. LDS repack -> coalesced 16B stores.
// ---------------------------------------------------------------------------
__global__ __launch_bounds__(256) void projqk_kernel(
    const float* __restrict__ Wq, const float* __restrict__ bq, const float* __restrict__ Xq,
    const float* __restrict__ Wk, const float* __restrict__ bk, const float* __restrict__ Xk,
    bf16_t* __restrict__ Qt, bf16_t* __restrict__ Kt)
{
    __shared__ __attribute__((aligned(16))) bf16_t T[64][40];  // [n_local][ck], +8 pad
    const int lane = threadIdx.x & 63, wave = threadIdx.x >> 6;
    const int g = lane >> 4, ln = lane & 15;
    const bool isK = (blockIdx.y == 1);
    const float* W    = isK ? Wk : Wq;
    const float* bias = isK ? bk : bq;
    const float* X  = (isK ? Xk : Xq) + (size_t)blockIdx.z * CFEAT * N_PIX;
    bf16_t*      Yt = (isK ? Kt : Qt) + (size_t)blockIdx.z * N_PIX * CKEY;
    const float qscale = isK ? 1.0f : 1.4426950408889634f;   // log2(e) folded into Q

    const int m_base = (wave & 1) * 16;                      // ck half
    const int n_loc  = (wave >> 1) * 32;                     // n half within block
    const int n_base = blockIdx.x * 64 + n_loc;

    f32x4 zero = {0.f, 0.f, 0.f, 0.f};
    f32x4 acc[2] = {zero, zero};
    for (int k0 = 0; k0 < CFEAT; k0 += 32) {
        bf16x8 a;
        const float* wp = W + (size_t)(m_base + ln) * CFEAT + k0 + g * 8;
#pragma unroll
        for (int j = 0; j < 8; ++j) a[j] = (bf16_t)wp[j];
#pragma unroll
        for (int nt = 0; nt < 2; ++nt) {
            const float* xp = X + (size_t)(k0 + g * 8) * N_PIX + n_base + nt * 16 + ln;
            bf16x8 bfr;
#pragma unroll
            for (int j = 0; j < 8; ++j) bfr[j] = (bf16_t)xp[(size_t)j * N_PIX];
            acc[nt] = mfma16(a, bfr, acc[nt]);
        }
    }
#pragma unroll
    for (int nt = 0; nt < 2; ++nt)
#pragma unroll
        for (int r = 0; r < 4; ++r) {
            const int ck = m_base + g * 4 + r;
            T[n_loc + nt * 16 + ln][ck] = (bf16_t)((acc[nt][r] + bias[ck]) * qscale);
        }
    __syncthreads();
    const int n  = threadIdx.x >> 2;
    const int sg = threadIdx.x & 3;
    bf16x8 row = *(const bf16x8*)&T[n][sg * 8];
    *(bf16x8*)&Yt[(size_t)(blockIdx.x * 64 + n) * CKEY + sg * 8] = row;
}

// ---------------------------------------------------------------------------
// projv (unchanged): V[b][c][n] = bf16(Wv.X + bv). grid (N/32, 2, B).
// ---------------------------------------------------------------------------
__global__ __launch_bounds__(256, 4) void projv_kernel(
    const float* __restrict__ W, const float* __restrict__ bias,
    const float* __restrict__ X, bf16_t* __restrict__ V)
{
    const int lane = threadIdx.x & 63, wave = threadIdx.x >> 6;
    const int g = lane >> 4, ln = lane & 15;
    const int b = blockIdx.z;
    const int n_base = blockIdx.x * 32;
    const int c_wave = blockIdx.y * 128 + wave * 32;
    const float* Xb = X + (size_t)b * CFEAT * N_PIX;
    bf16_t*      Vb = V + (size_t)b * CFEAT * N_PIX;

    f32x4 zero = {0.f, 0.f, 0.f, 0.f};
    f32x4 acc[2][2];
#pragma unroll
    for (int mt = 0; mt < 2; ++mt) { acc[mt][0] = zero; acc[mt][1] = zero; }

    for (int k0 = 0; k0 < CFEAT; k0 += 32) {
        bf16x8 bfr[2];
#pragma unroll
        for (int nt = 0; nt < 2; ++nt) {
            const float* xp = Xb + (size_t)(k0 + g * 8) * N_PIX + n_base + nt * 16 + ln;
#pragma unroll
            for (int j = 0; j < 8; ++j) bfr[nt][j] = (bf16_t)xp[(size_t)j * N_PIX];
        }
#pragma unroll
        for (int mt = 0; mt < 2; ++mt) {
            const float* wp = W + (size_t)(c_wave + mt * 16 + ln) * CFEAT + k0 + g * 8;
            bf16x8 a;
#pragma unroll
            for (int j = 0; j < 8; ++j) a[j] = (bf16_t)wp[j];
            acc[mt][0] = mfma16(a, bfr[0], acc[mt][0]);
            acc[mt][1] = mfma16(a, bfr[1], acc[mt][1]);
        }
    }
#pragma unroll
    for (int mt = 0; mt < 2; ++mt)
#pragma unroll
        for (int nt = 0; nt < 2; ++nt)
#pragma unroll
            for (int r = 0; r < 4; ++r) {
                const int m = c_wave + mt * 16 + g * 4 + r;
                const int n = n_base + nt * 16 + ln;
                Vb[(size_t)m * N_PIX + n] = (bf16_t)(acc[mt][nt][r] + bias[m]);
            }
}

// ---------------------------------------------------------------------------
// pv: out = gamma * softmax(QK^T) V / l + features (max-free softmax).
// This round (T4 + T12 + software pipeline):
//   - 4-deep V ring buffer (4 x 8KB), prefetch distance 2, RAW s_barrier with
//     counted vmcnt(2): the in-flight stage(n+2) is NEVER drained at the
//     barrier (old __syncthreads drained the just-issued DMA every iter).
//   - K loads for tile n+1 issued BEFORE stage(n+2), so the compiler's
//     in-order vmcnt wait for K implies stage(n+1) completion for free.
//   - P stays in registers: cvt_pk pairs + permlane32/16_swap reproduce the
//     PV B-fragment layout (no Plds, no LDS bank conflicts, no lgkm chain).
//   - V fragments for tile n ds_read at iteration TOP (guaranteed by the
//     previous barrier), overlapping LDS latency with S^T/exp of tile n+1.
//   - softmax in 2^x domain (Q pre-scaled by log2e in projqk).
// grid (4 c-splits, 64 i-tiles, B) = 1024 blocks; 4 blocks/CU, 32KB LDS.
// ---------------------------------------------------------------------------
__global__ __launch_bounds__(256, 4) void pv_kernel(
    const bf16_t* __restrict__ Qt, const bf16_t* __restrict__ Kt,
    const bf16_t* __restrict__ V,
    const float* __restrict__ features, const float* __restrict__ gamma,
    float* __restrict__ out)
{
    __shared__ __attribute__((aligned(16))) bf16_t Vlds[4][64 * 64];  // 4 x 8KB ring

    const int lane = threadIdx.x & 63, wave = threadIdx.x >> 6;
    const int g = lane >> 4, ln = lane & 15;
    const int b = blockIdx.z;
    const int i_base = blockIdx.y * 64 + wave * 16;
    const int c_base = blockIdx.x * 64;

    const bf16_t* Qb = Qt + (size_t)b * N_PIX * CKEY;
    const bf16_t* Kb = Kt + (size_t)b * N_PIX * CKEY;
    const bf16_t* Vb = V + (size_t)b * CFEAT * N_PIX;

    // staging map for this thread's two 16B chunks: slot s -> (c, jc)
    // s in [0,512): c = s>>3, stored jc = (s&7) ^ (c&7)  (XOR swizzle)
    const int s0 = wave * 128 + lane;
    const int s1 = s0 + 64;
    const int sc0 = s0 >> 3, sj0 = (s0 & 7) ^ (sc0 & 7);
    const int sc1 = s1 >> 3, sj1 = (s1 & 7) ^ (sc1 & 7);
    const bf16_t* vg0 = Vb + (size_t)(c_base + sc0) * N_PIX + sj0 * 8;
    const bf16_t* vg1 = Vb + (size_t)(c_base + sc1) * N_PIX + sj1 * 8;

    // B-frag for S^T: B[k=ck][n=i=ln] = Qt[i][ck]  (Q pre-scaled by log2e)
    const bf16x8 qf = *(const bf16x8*)&Qb[(size_t)(i_base + ln) * CKEY + g * 8];

    f32x4 zero = {0.f, 0.f, 0.f, 0.f};
    f32x4 acc[4] = {zero, zero, zero, zero};
    float ls0 = 0.f, ls1 = 0.f, ls2 = 0.f, ls3 = 0.f;

    // ---------------- prologue: P(0); stage tiles 0,1 ----------------
    bf16x8 pa0c, pa1c;
    {
        bf16x8 kf[4];
#pragma unroll
        for (int jt = 0; jt < 4; ++jt)
            kf[jt] = *(const bf16x8*)&Kb[(size_t)(jt * 16 + ln) * CKEY + g * 8];
        asm volatile("" ::: "memory");   // keep K loads issued before the DMAs
        glds16(vg0,      &Vlds[0][wave * 1024]);
        glds16(vg1,      &Vlds[0][wave * 1024 + 512]);
        glds16(vg0 + 64, &Vlds[1][wave * 1024]);
        glds16(vg1 + 64, &Vlds[1][wave * 1024 + 512]);
        softmax_tile(kf, qf, true, ls0, ls1, ls2, ls3, pa0c, pa1c);
        // wait for stage(0) only (leaves stage(1) in flight), publish to block
        asm volatile("s_waitcnt vmcnt(2)" ::: "memory");
        __builtin_amdgcn_s_barrier();
        asm volatile("" ::: "memory");
    }

    for (int n = 0; n < 64; ++n) {
        // ---- V fragments for tile n: safe any time after barrier(n-1);
        //      buf[n&3] is not overwritten until stage(n+4) (two barriers away)
        const bf16_t* Vt = &Vlds[n & 3][0];
        bf16x8 vf[8];
#pragma unroll
        for (int ct = 0; ct < 4; ++ct) {
            const int c = ct * 16 + ln;
            vf[2 * ct]     = *(const bf16x8*)&Vt[(c * 8 + ( g      ^ (c & 7))) * 8];
            vf[2 * ct + 1] = *(const bf16x8*)&Vt[(c * 8 + ((4 + g) ^ (c & 7))) * 8];
        }

        // ---- K frags for tile n+1 (wrapped on last iter; extra work only) ----
        const int jq = ((n + 1) & 63) * 64;
        bf16x8 kf[4];
#pragma unroll
        for (int jt = 0; jt < 4; ++jt)
            kf[jt] = *(const bf16x8*)&Kb[(size_t)(jq + jt * 16 + ln) * CKEY + g * 8];
        asm volatile("" ::: "memory");   // K loads stay BEFORE the stage DMAs

        // ---- stage tile n+2 into ring slot (n+2)&3 ----
        const int jn = (n * 64 + 128) & (N_PIX - 1);
        bf16_t* ldst = &Vlds[(n + 2) & 3][wave * 1024];
        glds16(vg0 + jn, ldst);
        glds16(vg1 + jn, ldst + 512);

        // ---- P(n+1): S^T -> exp2 -> in-register B-frags (no LDS) ----
        bf16x8 pa0n, pa1n;
        softmax_tile(kf, qf, n < 63, ls0, ls1, ls2, ls3, pa0n, pa1n);

        // ---- counted fence + raw barrier: stage(n+1) complete (implied by
        //      the in-order K wait), stage(n+2) stays in flight ----
        asm volatile("s_waitcnt vmcnt(2)" ::: "memory");
        __builtin_amdgcn_s_barrier();
        asm volatile("" ::: "memory");

        // ---- PV(n): A = V frags (already in regs), B = P^T frags ----
#pragma unroll
        for (int ct = 0; ct < 4; ++ct) {
            acc[ct] = mfma16(vf[2 * ct],     pa0c, acc[ct]);
            acc[ct] = mfma16(vf[2 * ct + 1], pa1c, acc[ct]);
        }
        pa0c = pa0n; pa1c = pa1n;
    }

    // l_i: sum the 4 g-group partials for i = ln
    float lsum = (ls0 + ls1) + (ls2 + ls3);
    lsum += __shfl_xor(lsum, 16);
    lsum += __shfl_xor(lsum, 32);
    const float s_lane = gamma[0] / lsum;

#pragma unroll
    for (int ct = 0; ct < 4; ++ct)
#pragma unroll
        for (int r = 0; r < 4; ++r) {
            const int c = c_base + ct * 16 + g * 4 + r;   // D row = c_local
            const int i = i_base + ln;                    // D col = i
            const size_t idx = ((size_t)b * CFEAT + c) * N_PIX + i;
            out[idx] = s_lane * acc[ct][r] + features[idx];
        }
}

// ---------------------------------------------------------------------------
extern "C" void kernel_launch(void* const* d_in, const int* in_sizes, int n_in,
                              void* d_out, int out_size, void* d_ws, size_t ws_size,
                              hipStream_t stream) {
    const float* features   = (const float*)d_in[0];
    const float* conditions = (const float*)d_in[1];
    const float* Wq  = (const float*)d_in[2];
    const float* bq  = (const float*)d_in[3];
    const float* Wk  = (const float*)d_in[4];
    const float* bk  = (const float*)d_in[5];
    const float* Wv  = (const float*)d_in[6];
    const float* bv  = (const float*)d_in[7];
    const float* gam = (const float*)d_in[8];
    float* out = (float*)d_out;

    // ws (bf16): Qt 1MB | Kt 1MB | V 8MB
    bf16_t* Qt = (bf16_t*)d_ws;
    bf16_t* Kt = Qt + (size_t)NBATCH * N_PIX * CKEY;
    bf16_t* Vw = Kt + (size_t)NBATCH * N_PIX * CKEY;

    projqk_kernel<<<dim3(N_PIX / 64, 2, NBATCH), 256, 0, stream>>>(
        Wq, bq, conditions, Wk, bk, features, Qt, Kt);
    projv_kernel<<<dim3(N_PIX / 32, 2, NBATCH), 256, 0, stream>>>(Wv, bv, features, Vw);
    pv_kernel<<<dim3(4, N_PIX / 64, NBATCH), 256, 0, stream>>>(
        Qt, Kt, Vw, features, gam, out);
}

// Round 2
// 172.850 us; speedup vs baseline: 1.1442x; 1.1166x over previous
//
#include <hip/hip_runtime.h>

typedef __bf16 bf16_t;
typedef __bf16 bf16x2 __attribute__((ext_vector_type(2)));
typedef __bf16 bf16x4 __attribute__((ext_vector_type(4)));
typedef __bf16 bf16x8 __attribute__((ext_vector_type(8)));
typedef float f32x4 __attribute__((ext_vector_type(4)));
typedef unsigned u32;
typedef unsigned u32x4 __attribute__((ext_vector_type(4)));

#define N_PIX 4096
#define CFEAT 256
#define CKEY 32
#define NBATCH 4

#if __has_builtin(__builtin_amdgcn_exp2f)
#define EXP2(x) __builtin_amdgcn_exp2f(x)
#else
#define EXP2(x) exp2f(x)
#endif

static __device__ __forceinline__ f32x4 mfma16(bf16x8 a, bf16x8 b, f32x4 c) {
    return __builtin_amdgcn_mfma_f32_16x16x32_bf16(a, b, c, 0, 0, 0);
}

// async global->LDS, 16B per lane; LDS dest = wave-uniform base + lane*16
static __device__ __forceinline__ void glds16(const void* g, void* l) {
    __builtin_amdgcn_global_load_lds(
        (const __attribute__((address_space(1))) void*)g,
        (__attribute__((address_space(3))) void*)l, 16, 0, 0);
}

// pack two f32 -> one dword of 2 bf16 (compiler emits v_cvt_pk_bf16_f32)
static __device__ __forceinline__ u32 pk2(float lo, float hi) {
    bf16x2 t; t[0] = (bf16_t)lo; t[1] = (bf16_t)hi;
    return __builtin_bit_cast(u32, t);
}

// 4-group transpose step (T12): on entry x,y live in all 4 lane-groups.
// On exit: x = (x@g0, x@g2, y@g0, y@g2), y = (x@g1, x@g3, y@g1, y@g3).
static __device__ __forceinline__ void xpose4(u32 &x, u32 &y) {
#if __has_builtin(__builtin_amdgcn_permlane32_swap) && __has_builtin(__builtin_amdgcn_permlane16_swap)
    auto r32 = __builtin_amdgcn_permlane32_swap(x, y, false, false);
    auto r16 = __builtin_amdgcn_permlane16_swap(r32[0], r32[1], false, false);
    x = r16[0]; y = r16[1];
#else
    const int lane = threadIdx.x & 63;
    const int g = lane >> 4, ln = lane & 15;
    const int i0 = ln + ((g & 1) << 5);
    const int i2 = i0 + 16;
    u32 xs0 = (u32)__shfl((int)x, i0), ys0 = (u32)__shfl((int)y, i0);
    u32 xs2 = (u32)__shfl((int)x, i2), ys2 = (u32)__shfl((int)y, i2);
    x = (g < 2) ? xs0 : ys0;
    y = (g < 2) ? xs2 : ys2;
#endif
}

// S^T tile (64 j x 16 i) -> exp2 -> in-register P fragments for the PV MFMAs.
// Row-sums folded into accsum via ones-MFMA (every row of D = full 32-j sum).
static __device__ __forceinline__ void softmax_tile(
    const bf16x8 kf[4], bf16x8 qf, bf16x8 ones,
    f32x4 &accsum, bf16x8 &pa0, bf16x8 &pa1)
{
    f32x4 zero = {0.f, 0.f, 0.f, 0.f};
    f32x4 st[4];
#pragma unroll
    for (int jt = 0; jt < 4; ++jt) st[jt] = mfma16(kf[jt], qf, zero);
    float ex[16];
#pragma unroll
    for (int jt = 0; jt < 4; ++jt)
#pragma unroll
        for (int r = 0; r < 4; ++r) ex[jt * 4 + r] = EXP2(st[jt][r]);
    u32 a0 = pk2(ex[0],  ex[1]),  a1 = pk2(ex[2],  ex[3]);
    u32 b0 = pk2(ex[4],  ex[5]),  b1 = pk2(ex[6],  ex[7]);
    u32 c0 = pk2(ex[8],  ex[9]),  c1 = pk2(ex[10], ex[11]);
    u32 d0 = pk2(ex[12], ex[13]), d1 = pk2(ex[14], ex[15]);
    xpose4(a0, b0); xpose4(a1, b1);
    xpose4(c0, d0); xpose4(c1, d1);
    u32x4 w0 = {a0, a1, b0, b1};
    u32x4 w1 = {c0, c1, d0, d1};
    pa0 = __builtin_bit_cast(bf16x8, w0);
    pa1 = __builtin_bit_cast(bf16x8, w1);
    // l_i partial: D[row][i] = sum_k P[k][i]  (all rows identical)
    accsum = mfma16(ones, pa0, accsum);
    accsum = mfma16(ones, pa1, accsum);
}

// ---------------------------------------------------------------------------
// projqk: Yt[b][n][32] = bf16(W.X + bias), transposed out. Q side pre-scaled
// by log2(e) so pv's softmax can use raw v_exp_f32 (2^x).
// ---------------------------------------------------------------------------
__global__ __launch_bounds__(256) void projqk_kernel(
    const float* __restrict__ Wq, const float* __restrict__ bq, const float* __restrict__ Xq,
    const float* __restrict__ Wk, const float* __restrict__ bk, const float* __restrict__ Xk,
    bf16_t* __restrict__ Qt, bf16_t* __restrict__ Kt)
{
    __shared__ __attribute__((aligned(16))) bf16_t T[64][40];  // [n_local][ck], +8 pad
    const int lane = threadIdx.x & 63, wave = threadIdx.x >> 6;
    const int g = lane >> 4, ln = lane & 15;
    const bool isK = (blockIdx.y == 1);
    const float* W    = isK ? Wk : Wq;
    const float* bias = isK ? bk : bq;
    const float* X  = (isK ? Xk : Xq) + (size_t)blockIdx.z * CFEAT * N_PIX;
    bf16_t*      Yt = (isK ? Kt : Qt) + (size_t)blockIdx.z * N_PIX * CKEY;
    const float qscale = isK ? 1.0f : 1.4426950408889634f;   // log2(e) folded into Q

    const int m_base = (wave & 1) * 16;                      // ck half
    const int n_loc  = (wave >> 1) * 32;                     // n half within block
    const int n_base = blockIdx.x * 64 + n_loc;

    f32x4 zero = {0.f, 0.f, 0.f, 0.f};
    f32x4 acc[2] = {zero, zero};
    for (int k0 = 0; k0 < CFEAT; k0 += 32) {
        bf16x8 a;
        const float* wp = W + (size_t)(m_base + ln) * CFEAT + k0 + g * 8;
#pragma unroll
        for (int j = 0; j < 8; ++j) a[j] = (bf16_t)wp[j];
#pragma unroll
        for (int nt = 0; nt < 2; ++nt) {
            const float* xp = X + (size_t)(k0 + g * 8) * N_PIX + n_base + nt * 16 + ln;
            bf16x8 bfr;
#pragma unroll
            for (int j = 0; j < 8; ++j) bfr[j] = (bf16_t)xp[(size_t)j * N_PIX];
            acc[nt] = mfma16(a, bfr, acc[nt]);
        }
    }
#pragma unroll
    for (int nt = 0; nt < 2; ++nt)
#pragma unroll
        for (int r = 0; r < 4; ++r) {
            const int ck = m_base + g * 4 + r;
            T[n_loc + nt * 16 + ln][ck] = (bf16_t)((acc[nt][r] + bias[ck]) * qscale);
        }
    __syncthreads();
    const int n  = threadIdx.x >> 2;
    const int sg = threadIdx.x & 3;
    bf16x8 row = *(const bf16x8*)&T[n][sg * 8];
    *(bf16x8*)&Yt[(size_t)(blockIdx.x * 64 + n) * CKEY + sg * 8] = row;
}

// ---------------------------------------------------------------------------
// projv (unchanged): V[b][c][n] = bf16(Wv.X + bv). grid (N/32, 2, B).
// ---------------------------------------------------------------------------
__global__ __launch_bounds__(256, 4) void projv_kernel(
    const float* __restrict__ W, const float* __restrict__ bias,
    const float* __restrict__ X, bf16_t* __restrict__ V)
{
    const int lane = threadIdx.x & 63, wave = threadIdx.x >> 6;
    const int g = lane >> 4, ln = lane & 15;
    const int b = blockIdx.z;
    const int n_base = blockIdx.x * 32;
    const int c_wave = blockIdx.y * 128 + wave * 32;
    const float* Xb = X + (size_t)b * CFEAT * N_PIX;
    bf16_t*      Vb = V + (size_t)b * CFEAT * N_PIX;

    f32x4 zero = {0.f, 0.f, 0.f, 0.f};
    f32x4 acc[2][2];
#pragma unroll
    for (int mt = 0; mt < 2; ++mt) { acc[mt][0] = zero; acc[mt][1] = zero; }

    for (int k0 = 0; k0 < CFEAT; k0 += 32) {
        bf16x8 bfr[2];
#pragma unroll
        for (int nt = 0; nt < 2; ++nt) {
            const float* xp = Xb + (size_t)(k0 + g * 8) * N_PIX + n_base + nt * 16 + ln;
#pragma unroll
            for (int j = 0; j < 8; ++j) bfr[nt][j] = (bf16_t)xp[(size_t)j * N_PIX];
        }
#pragma unroll
        for (int mt = 0; mt < 2; ++mt) {
            const float* wp = W + (size_t)(c_wave + mt * 16 + ln) * CFEAT + k0 + g * 8;
            bf16x8 a;
#pragma unroll
            for (int j = 0; j < 8; ++j) a[j] = (bf16_t)wp[j];
            acc[mt][0] = mfma16(a, bfr[0], acc[mt][0]);
            acc[mt][1] = mfma16(a, bfr[1], acc[mt][1]);
        }
    }
#pragma unroll
    for (int mt = 0; mt < 2; ++mt)
#pragma unroll
        for (int nt = 0; nt < 2; ++nt)
#pragma unroll
            for (int r = 0; r < 4; ++r) {
                const int m = c_wave + mt * 16 + g * 4 + r;
                const int n = n_base + nt * 16 + ln;
                Vb[(size_t)m * N_PIX + n] = (bf16_t)(acc[mt][nt][r] + bias[m]);
            }
}

// ---------------------------------------------------------------------------
// pv: out = gamma * softmax(QK^T) V / l + features (max-free softmax).
// This round: c-split 4 -> 2 (block = 128c x 64i; halves exp/S/K redundancy),
// K prefetch distance 2 (ping-pong regs, 2x-unrolled loop), l-sum via
// ones-MFMA (kills 16 v_add/iter + final shuffle reduce).
//   - 4-deep V ring (4 x 16KB = 64KB), stage distance 2, counted vmcnt(8)
//     fence + raw s_barrier: K(n+2)x4 + stage(n+2)x4 stay in flight.
//   - P stays in registers (cvt_pk + permlane32/16_swap), no Plds.
//   - V frags split: 8 ds_read pre-barrier, 8 post-barrier (VGPR cap).
// grid (2 c-splits, 64 i-tiles, B) = 512 blocks = 2 blocks/CU.
// ---------------------------------------------------------------------------
__global__ __launch_bounds__(256, 2) void pv_kernel(
    const bf16_t* __restrict__ Qt, const bf16_t* __restrict__ Kt,
    const bf16_t* __restrict__ V,
    const float* __restrict__ features, const float* __restrict__ gamma,
    float* __restrict__ out)
{
    __shared__ __attribute__((aligned(16))) bf16_t Vlds[4][128 * 64];  // 4 x 16KB ring

    const int lane = threadIdx.x & 63, wave = threadIdx.x >> 6;
    const int g = lane >> 4, ln = lane & 15;
    const int b = blockIdx.z;
    const int i_base = blockIdx.y * 64 + wave * 16;
    const int c_base = blockIdx.x * 128;

    const bf16_t* Qb = Qt + (size_t)b * N_PIX * CKEY;
    const bf16_t* Kb = Kt + (size_t)b * N_PIX * CKEY;
    const bf16_t* Vb = V + (size_t)b * CFEAT * N_PIX;

    // staging map: slot s in [0,1024): c = s>>3, jc = (s&7)^(c&7) (XOR swizzle)
    const int s0 = wave * 256 + lane, s1 = s0 + 64, s2 = s0 + 128, s3 = s0 + 192;
    const int sc0 = s0 >> 3, sj0 = (s0 & 7) ^ (sc0 & 7);
    const int sc1 = s1 >> 3, sj1 = (s1 & 7) ^ (sc1 & 7);
    const int sc2 = s2 >> 3, sj2 = (s2 & 7) ^ (sc2 & 7);
    const int sc3 = s3 >> 3, sj3 = (s3 & 7) ^ (sc3 & 7);
    const bf16_t* vg0 = Vb + (size_t)(c_base + sc0) * N_PIX + sj0 * 8;
    const bf16_t* vg1 = Vb + (size_t)(c_base + sc1) * N_PIX + sj1 * 8;
    const bf16_t* vg2 = Vb + (size_t)(c_base + sc2) * N_PIX + sj2 * 8;
    const bf16_t* vg3 = Vb + (size_t)(c_base + sc3) * N_PIX + sj3 * 8;

    // B-frag for S^T: B[k=ck][n=i=ln] = Qt[i][ck]  (Q pre-scaled by log2e)
    const bf16x8 qf = *(const bf16x8*)&Qb[(size_t)(i_base + ln) * CKEY + g * 8];

    bf16x8 ones;
#pragma unroll
    for (int j = 0; j < 8; ++j) ones[j] = (bf16_t)1.0f;

    f32x4 zero = {0.f, 0.f, 0.f, 0.f};
    f32x4 acc[8] = {zero, zero, zero, zero, zero, zero, zero, zero};
    f32x4 accsum = zero;

    bf16x8 kfA[4], kfB[4];
    bf16x8 pa0c, pa1c;

    // ---------------- prologue: P(0); stage tiles 0,1; issue K(1) ----------
    {
        bf16x8 kf0[4];
#pragma unroll
        for (int jt = 0; jt < 4; ++jt)
            kf0[jt] = *(const bf16x8*)&Kb[(size_t)(jt * 16 + ln) * CKEY + g * 8];
        asm volatile("" ::: "memory");   // K(0) issued before the DMAs
        glds16(vg0, &Vlds[0][wave * 2048]);
        glds16(vg1, &Vlds[0][wave * 2048 + 512]);
        glds16(vg2, &Vlds[0][wave * 2048 + 1024]);
        glds16(vg3, &Vlds[0][wave * 2048 + 1536]);
        glds16(vg0 + 64, &Vlds[1][wave * 2048]);
        glds16(vg1 + 64, &Vlds[1][wave * 2048 + 512]);
        glds16(vg2 + 64, &Vlds[1][wave * 2048 + 1024]);
        glds16(vg3 + 64, &Vlds[1][wave * 2048 + 1536]);
#pragma unroll
        for (int jt = 0; jt < 4; ++jt)
            kfA[jt] = *(const bf16x8*)&Kb[(size_t)(64 + jt * 16 + ln) * CKEY + g * 8];
        softmax_tile(kf0, qf, ones, accsum, pa0c, pa1c);
        // stage(0) done; stage(1)x4 + K(1)x4 stay in flight
        asm volatile("s_waitcnt vmcnt(8)" ::: "memory");
        __builtin_amdgcn_s_barrier();
        asm volatile("" ::: "memory");
    }

// one pipelined iteration: PV(n) with V(n)+P(n); softmax(n+1) with KFU=K(n+1);
// issue KFN=K(n+2); stage V(n+2). Fence: vmcnt(8) = K(n+2)x4 + stage(n+2)x4.
#define PV_ITER(NN, KFU, KFN)                                                  \
  {                                                                            \
    const int nn = (NN);                                                       \
    const bf16_t* Vt = &Vlds[nn & 3][0];                                       \
    bf16x8 vfl[8];                                                             \
    _Pragma("unroll")                                                          \
    for (int ct = 0; ct < 4; ++ct) {                                           \
      const int c = ct * 16 + ln;                                              \
      vfl[2 * ct]     = *(const bf16x8*)&Vt[(c * 8 + ( g      ^ (c & 7))) * 8];\
      vfl[2 * ct + 1] = *(const bf16x8*)&Vt[(c * 8 + ((4 + g) ^ (c & 7))) * 8];\
    }                                                                          \
    const int jq2 = ((nn + 2) & 63) * 64;                                      \
    _Pragma("unroll")                                                          \
    for (int jt = 0; jt < 4; ++jt)                                             \
      KFN[jt] = *(const bf16x8*)&Kb[(size_t)(jq2 + jt * 16 + ln) * CKEY + g * 8]; \
    asm volatile("" ::: "memory");  /* K loads stay BEFORE the stage DMAs */   \
    const int jn = (nn * 64 + 128) & (N_PIX - 1);                              \
    bf16_t* ldst = &Vlds[(nn + 2) & 3][wave * 2048];                           \
    glds16(vg0 + jn, ldst);                                                    \
    glds16(vg1 + jn, ldst + 512);                                              \
    glds16(vg2 + jn, ldst + 1024);                                             \
    glds16(vg3 + jn, ldst + 1536);                                             \
    bf16x8 pa0n, pa1n;                                                         \
    const bool live = (nn < 63);                                               \
    if (live) softmax_tile(KFU, qf, ones, accsum, pa0n, pa1n);                 \
    asm volatile("s_waitcnt vmcnt(8)" ::: "memory");                           \
    __builtin_amdgcn_s_barrier();                                              \
    asm volatile("" ::: "memory");                                             \
    bf16x8 vfh[8];                                                             \
    _Pragma("unroll")                                                          \
    for (int ct = 4; ct < 8; ++ct) {                                           \
      const int c = ct * 16 + ln;                                              \
      vfh[2 * (ct - 4)]     = *(const bf16x8*)&Vt[(c * 8 + ( g      ^ (c & 7))) * 8]; \
      vfh[2 * (ct - 4) + 1] = *(const bf16x8*)&Vt[(c * 8 + ((4 + g) ^ (c & 7))) * 8]; \
    }                                                                          \
    _Pragma("unroll")                                                          \
    for (int ct = 0; ct < 4; ++ct) {                                           \
      acc[ct] = mfma16(vfl[2 * ct],     pa0c, acc[ct]);                        \
      acc[ct] = mfma16(vfl[2 * ct + 1], pa1c, acc[ct]);                        \
    }                                                                          \
    _Pragma("unroll")                                                          \
    for (int ct = 0; ct < 4; ++ct) {                                           \
      acc[4 + ct] = mfma16(vfh[2 * ct],     pa0c, acc[4 + ct]);                \
      acc[4 + ct] = mfma16(vfh[2 * ct + 1], pa1c, acc[4 + ct]);                \
    }                                                                          \
    if (live) { pa0c = pa0n; pa1c = pa1n; }                                    \
  }

    for (int n2 = 0; n2 < 32; ++n2) {
        PV_ITER(2 * n2,     kfA, kfB);
        PV_ITER(2 * n2 + 1, kfB, kfA);
    }
#undef PV_ITER

    // l_i: accsum rows are all identical = full sum over j for i = ln
    const float s_lane = gamma[0] / accsum[0];

#pragma unroll
    for (int ct = 0; ct < 8; ++ct)
#pragma unroll
        for (int r = 0; r < 4; ++r) {
            const int c = c_base + ct * 16 + g * 4 + r;   // D row = c_local
            const int i = i_base + ln;                    // D col = i
            const size_t idx = ((size_t)b * CFEAT + c) * N_PIX + i;
            out[idx] = s_lane * acc[ct][r] + features[idx];
        }
}

// ---------------------------------------------------------------------------
extern "C" void kernel_launch(void* const* d_in, const int* in_sizes, int n_in,
                              void* d_out, int out_size, void* d_ws, size_t ws_size,
                              hipStream_t stream) {
    const float* features   = (const float*)d_in[0];
    const float* conditions = (const float*)d_in[1];
    const float* Wq  = (const float*)d_in[2];
    const float* bq  = (const float*)d_in[3];
    const float* Wk  = (const float*)d_in[4];
    const float* bk  = (const float*)d_in[5];
    const float* Wv  = (const float*)d_in[6];
    const float* bv  = (const float*)d_in[7];
    const float* gam = (const float*)d_in[8];
    float* out = (float*)d_out;

    // ws (bf16): Qt 1MB | Kt 1MB | V 8MB
    bf16_t* Qt = (bf16_t*)d_ws;
    bf16_t* Kt = Qt + (size_t)NBATCH * N_PIX * CKEY;
    bf16_t* Vw = Kt + (size_t)NBATCH * N_PIX * CKEY;

    projqk_kernel<<<dim3(N_PIX / 64, 2, NBATCH), 256, 0, stream>>>(
        Wq, bq, conditions, Wk, bk, features, Qt, Kt);
    projv_kernel<<<dim3(N_PIX / 32, 2, NBATCH), 256, 0, stream>>>(Wv, bv, features, Vw);
    pv_kernel<<<dim3(2, N_PIX / 64, NBATCH), 256, 0, stream>>>(
        Qt, Kt, Vw, features, gam, out);
}

// Round 4
// 169.449 us; speedup vs baseline: 1.1671x; 1.0201x over previous
//
#include <hip/hip_runtime.h>

typedef __bf16 bf16_t;
typedef __bf16 bf16x2 __attribute__((ext_vector_type(2)));
typedef __bf16 bf16x4 __attribute__((ext_vector_type(4)));
typedef __bf16 bf16x8 __attribute__((ext_vector_type(8)));
typedef float f32x4 __attribute__((ext_vector_type(4)));
typedef unsigned u32;
typedef unsigned u32x4 __attribute__((ext_vector_type(4)));

#define N_PIX 4096
#define CFEAT 256
#define CKEY 32
#define NBATCH 4

#if __has_builtin(__builtin_amdgcn_exp2f)
#define EXP2(x) __builtin_amdgcn_exp2f(x)
#else
#define EXP2(x) exp2f(x)
#endif

static __device__ __forceinline__ f32x4 mfma16(bf16x8 a, bf16x8 b, f32x4 c) {
    return __builtin_amdgcn_mfma_f32_16x16x32_bf16(a, b, c, 0, 0, 0);
}

// async global->LDS, 16B per lane; LDS dest = wave-uniform base + lane*16
static __device__ __forceinline__ void glds16(const void* g, void* l) {
    __builtin_amdgcn_global_load_lds(
        (const __attribute__((address_space(1))) void*)g,
        (__attribute__((address_space(3))) void*)l, 16, 0, 0);
}

// pack two f32 -> one dword of 2 bf16 (compiler emits v_cvt_pk_bf16_f32)
static __device__ __forceinline__ u32 pk2(float lo, float hi) {
    bf16x2 t; t[0] = (bf16_t)lo; t[1] = (bf16_t)hi;
    return __builtin_bit_cast(u32, t);
}

// 4-group transpose step (T12): on entry x,y live in all 4 lane-groups.
// On exit: x = (x@g0, x@g2, y@g0, y@g2), y = (x@g1, x@g3, y@g1, y@g3).
static __device__ __forceinline__ void xpose4(u32 &x, u32 &y) {
#if __has_builtin(__builtin_amdgcn_permlane32_swap) && __has_builtin(__builtin_amdgcn_permlane16_swap)
    auto r32 = __builtin_amdgcn_permlane32_swap(x, y, false, false);
    auto r16 = __builtin_amdgcn_permlane16_swap(r32[0], r32[1], false, false);
    x = r16[0]; y = r16[1];
#else
    const int lane = threadIdx.x & 63;
    const int g = lane >> 4, ln = lane & 15;
    const int i0 = ln + ((g & 1) << 5);
    const int i2 = i0 + 16;
    u32 xs0 = (u32)__shfl((int)x, i0), ys0 = (u32)__shfl((int)y, i0);
    u32 xs2 = (u32)__shfl((int)x, i2), ys2 = (u32)__shfl((int)y, i2);
    x = (g < 2) ? xs0 : ys0;
    y = (g < 2) ? xs2 : ys2;
#endif
}

// S^T tile (64 j x 16 i) -> exp2 -> in-register P fragments for the PV MFMAs.
// Row-sums folded into accsum via ones-MFMA (every row of D = full 32-j sum).
static __device__ __forceinline__ void softmax_tile(
    const bf16x8 kf[4], bf16x8 qf, bf16x8 ones,
    f32x4 &accsum, bf16x8 &pa0, bf16x8 &pa1)
{
    f32x4 zero = {0.f, 0.f, 0.f, 0.f};
    f32x4 st[4];
#pragma unroll
    for (int jt = 0; jt < 4; ++jt) st[jt] = mfma16(kf[jt], qf, zero);
    float ex[16];
#pragma unroll
    for (int jt = 0; jt < 4; ++jt)
#pragma unroll
        for (int r = 0; r < 4; ++r) ex[jt * 4 + r] = EXP2(st[jt][r]);
    u32 a0 = pk2(ex[0],  ex[1]),  a1 = pk2(ex[2],  ex[3]);
    u32 b0 = pk2(ex[4],  ex[5]),  b1 = pk2(ex[6],  ex[7]);
    u32 c0 = pk2(ex[8],  ex[9]),  c1 = pk2(ex[10], ex[11]);
    u32 d0 = pk2(ex[12], ex[13]), d1 = pk2(ex[14], ex[15]);
    xpose4(a0, b0); xpose4(a1, b1);
    xpose4(c0, d0); xpose4(c1, d1);
    u32x4 w0 = {a0, a1, b0, b1};
    u32x4 w1 = {c0, c1, d0, d1};
    pa0 = __builtin_bit_cast(bf16x8, w0);
    pa1 = __builtin_bit_cast(bf16x8, w1);
    // l_i partial: D[row][i] = sum_k P[k][i]  (all rows identical)
    accsum = mfma16(ones, pa0, accsum);
    accsum = mfma16(ones, pa1, accsum);
}

// ---------------------------------------------------------------------------
// proj_kernel (fused): one launch produces Qt, Kt (transposed bf16, Q scaled
// by log2e) and V (bf16 [c][n]).
//   blocks [0,256):    Q  (xt = id&63, b = id>>6)   — from conditions
//   blocks [256,512):  K  (same decode)             — from features
//   blocks [512,1024): V  (xt = id&127, b = id>>7)  — from features,
//                      all 256 channels per block (features read ONCE).
// ---------------------------------------------------------------------------
__global__ __launch_bounds__(256) void proj_kernel(
    const float* __restrict__ Wq, const float* __restrict__ bq, const float* __restrict__ cond,
    const float* __restrict__ Wk, const float* __restrict__ bk, const float* __restrict__ feat,
    const float* __restrict__ Wv, const float* __restrict__ bv,
    bf16_t* __restrict__ Qt, bf16_t* __restrict__ Kt, bf16_t* __restrict__ Vv)
{
    __shared__ __attribute__((aligned(16))) bf16_t T[64][40];  // QK repack, +8 pad
    const int lane = threadIdx.x & 63, wave = threadIdx.x >> 6;
    const int g = lane >> 4, ln = lane & 15;
    const int bid = blockIdx.x;
    f32x4 zero = {0.f, 0.f, 0.f, 0.f};

    if (bid < 512) {
        // ---------------- Q / K projection (transposed output) ----------------
        const bool isK = (bid >= 256);
        const int idx = bid & 255;
        const int xt = idx & 63;
        const int b  = idx >> 6;
        const float* W    = isK ? Wk : Wq;
        const float* bias = isK ? bk : bq;
        const float* X  = (isK ? feat : cond) + (size_t)b * CFEAT * N_PIX;
        bf16_t*      Yt = (isK ? Kt : Qt) + (size_t)b * N_PIX * CKEY;
        const float qscale = isK ? 1.0f : 1.4426950408889634f;  // log2(e) into Q

        const int m_base = (wave & 1) * 16;                     // ck half
        const int n_loc  = (wave >> 1) * 32;                    // n half in block
        const int n_base = xt * 64 + n_loc;

        f32x4 acc[2] = {zero, zero};
        for (int k0 = 0; k0 < CFEAT; k0 += 32) {
            bf16x8 a;
            const float* wp = W + (size_t)(m_base + ln) * CFEAT + k0 + g * 8;
#pragma unroll
            for (int j = 0; j < 8; ++j) a[j] = (bf16_t)wp[j];
#pragma unroll
            for (int nt = 0; nt < 2; ++nt) {
                const float* xp = X + (size_t)(k0 + g * 8) * N_PIX + n_base + nt * 16 + ln;
                bf16x8 bfr;
#pragma unroll
                for (int j = 0; j < 8; ++j) bfr[j] = (bf16_t)xp[(size_t)j * N_PIX];
                acc[nt] = mfma16(a, bfr, acc[nt]);
            }
        }
#pragma unroll
        for (int nt = 0; nt < 2; ++nt)
#pragma unroll
            for (int r = 0; r < 4; ++r) {
                const int ck = m_base + g * 4 + r;
                T[n_loc + nt * 16 + ln][ck] = (bf16_t)((acc[nt][r] + bias[ck]) * qscale);
            }
        __syncthreads();
        const int n  = threadIdx.x >> 2;
        const int sg = threadIdx.x & 3;
        bf16x8 row = *(const bf16x8*)&T[n][sg * 8];
        *(bf16x8*)&Yt[(size_t)(xt * 64 + n) * CKEY + sg * 8] = row;
    } else {
        // ---------------- V projection: 256 channels x 32 n per block ---------
        const int idx = bid - 512;
        const int xt = idx & 127;
        const int b  = idx >> 7;
        const int n_base = xt * 32;
        const int c_wave = wave * 64;                           // 64 ch per wave
        const float* Xb = feat + (size_t)b * CFEAT * N_PIX;
        bf16_t*      Vb = Vv + (size_t)b * CFEAT * N_PIX;

        f32x4 acc[4][2];
#pragma unroll
        for (int mt = 0; mt < 4; ++mt) { acc[mt][0] = zero; acc[mt][1] = zero; }

        for (int k0 = 0; k0 < CFEAT; k0 += 32) {
            bf16x8 bfr[2];
#pragma unroll
            for (int nt = 0; nt < 2; ++nt) {
                const float* xp = Xb + (size_t)(k0 + g * 8) * N_PIX + n_base + nt * 16 + ln;
#pragma unroll
                for (int j = 0; j < 8; ++j) bfr[nt][j] = (bf16_t)xp[(size_t)j * N_PIX];
            }
#pragma unroll
            for (int mt = 0; mt < 4; ++mt) {
                const float* wp = Wv + (size_t)(c_wave + mt * 16 + ln) * CFEAT + k0 + g * 8;
                bf16x8 a;
#pragma unroll
                for (int j = 0; j < 8; ++j) a[j] = (bf16_t)wp[j];
                acc[mt][0] = mfma16(a, bfr[0], acc[mt][0]);
                acc[mt][1] = mfma16(a, bfr[1], acc[mt][1]);
            }
        }
#pragma unroll
        for (int mt = 0; mt < 4; ++mt)
#pragma unroll
            for (int nt = 0; nt < 2; ++nt)
#pragma unroll
                for (int r = 0; r < 4; ++r) {
                    const int m = c_wave + mt * 16 + g * 4 + r;
                    const int n = n_base + nt * 16 + ln;
                    Vb[(size_t)m * N_PIX + n] = (bf16_t)(acc[mt][nt][r] + bv[m]);
                }
    }
}

// ---------------------------------------------------------------------------
// pv: out = gamma * softmax(QK^T) V / l + features (max-free softmax).
//   - block = 128c x 64i, grid (2, 64, B) = 512 blocks = 2 blocks/CU.
//   - 4-deep V ring (4 x 16KB = 64KB LDS), stage distance 2, counted vmcnt(8)
//     fence + raw s_barrier (K(n+2)x4 + stage(n+2)x4 stay in flight).
//   - ALL 16 V-fragment ds_read_b128 at iteration top -> post-barrier section
//     is pure MFMA; s_setprio(1) around it (T5, role-diverse blocks).
//   - P in registers (cvt_pk + permlane32/16_swap); l-sum via ones-MFMA.
// ---------------------------------------------------------------------------
__global__ __launch_bounds__(256, 2) void pv_kernel(
    const bf16_t* __restrict__ Qt, const bf16_t* __restrict__ Kt,
    const bf16_t* __restrict__ V,
    const float* __restrict__ features, const float* __restrict__ gamma,
    float* __restrict__ out)
{
    __shared__ __attribute__((aligned(16))) bf16_t Vlds[4][128 * 64];  // 4 x 16KB ring

    const int lane = threadIdx.x & 63, wave = threadIdx.x >> 6;
    const int g = lane >> 4, ln = lane & 15;
    const int b = blockIdx.z;
    const int i_base = blockIdx.y * 64 + wave * 16;
    const int c_base = blockIdx.x * 128;

    const bf16_t* Qb = Qt + (size_t)b * N_PIX * CKEY;
    const bf16_t* Kb = Kt + (size_t)b * N_PIX * CKEY;
    const bf16_t* Vb = V + (size_t)b * CFEAT * N_PIX;

    // staging map: slot s in [0,1024): c = s>>3, jc = (s&7)^(c&7) (XOR swizzle)
    const int s0 = wave * 256 + lane, s1 = s0 + 64, s2 = s0 + 128, s3 = s0 + 192;
    const int sc0 = s0 >> 3, sj0 = (s0 & 7) ^ (sc0 & 7);
    const int sc1 = s1 >> 3, sj1 = (s1 & 7) ^ (sc1 & 7);
    const int sc2 = s2 >> 3, sj2 = (s2 & 7) ^ (sc2 & 7);
    const int sc3 = s3 >> 3, sj3 = (s3 & 7) ^ (sc3 & 7);
    const bf16_t* vg0 = Vb + (size_t)(c_base + sc0) * N_PIX + sj0 * 8;
    const bf16_t* vg1 = Vb + (size_t)(c_base + sc1) * N_PIX + sj1 * 8;
    const bf16_t* vg2 = Vb + (size_t)(c_base + sc2) * N_PIX + sj2 * 8;
    const bf16_t* vg3 = Vb + (size_t)(c_base + sc3) * N_PIX + sj3 * 8;

    // B-frag for S^T: B[k=ck][n=i=ln] = Qt[i][ck]  (Q pre-scaled by log2e)
    const bf16x8 qf = *(const bf16x8*)&Qb[(size_t)(i_base + ln) * CKEY + g * 8];

    bf16x8 ones;
#pragma unroll
    for (int j = 0; j < 8; ++j) ones[j] = (bf16_t)1.0f;

    f32x4 zero = {0.f, 0.f, 0.f, 0.f};
    f32x4 acc[8] = {zero, zero, zero, zero, zero, zero, zero, zero};
    f32x4 accsum = zero;

    bf16x8 kfA[4], kfB[4];
    bf16x8 pa0c, pa1c;

    // ---------------- prologue: P(0); stage tiles 0,1; issue K(1) ----------
    {
        bf16x8 kf0[4];
#pragma unroll
        for (int jt = 0; jt < 4; ++jt)
            kf0[jt] = *(const bf16x8*)&Kb[(size_t)(jt * 16 + ln) * CKEY + g * 8];
        asm volatile("" ::: "memory");   // K(0) issued before the DMAs
        glds16(vg0, &Vlds[0][wave * 2048]);
        glds16(vg1, &Vlds[0][wave * 2048 + 512]);
        glds16(vg2, &Vlds[0][wave * 2048 + 1024]);
        glds16(vg3, &Vlds[0][wave * 2048 + 1536]);
        glds16(vg0 + 64, &Vlds[1][wave * 2048]);
        glds16(vg1 + 64, &Vlds[1][wave * 2048 + 512]);
        glds16(vg2 + 64, &Vlds[1][wave * 2048 + 1024]);
        glds16(vg3 + 64, &Vlds[1][wave * 2048 + 1536]);
#pragma unroll
        for (int jt = 0; jt < 4; ++jt)
            kfA[jt] = *(const bf16x8*)&Kb[(size_t)(64 + jt * 16 + ln) * CKEY + g * 8];
        softmax_tile(kf0, qf, ones, accsum, pa0c, pa1c);
        // stage(0) done; stage(1)x4 + K(1)x4 stay in flight
        asm volatile("s_waitcnt vmcnt(8)" ::: "memory");
        __builtin_amdgcn_s_barrier();
        asm volatile("" ::: "memory");
    }

// one pipelined iteration: PV(n) with V(n)+P(n); softmax(n+1) with KFU=K(n+1);
// issue KFN=K(n+2); stage V(n+2). Fence: vmcnt(8) = K(n+2)x4 + stage(n+2)x4.
#define PV_ITER(NN, KFU, KFN)                                                  \
  {                                                                            \
    const int nn = (NN);                                                       \
    const bf16_t* Vt = &Vlds[nn & 3][0];                                       \
    bf16x8 vf[16];                                                             \
    _Pragma("unroll")                                                          \
    for (int ct = 0; ct < 8; ++ct) {                                           \
      const int c = ct * 16 + ln;                                              \
      vf[2 * ct]     = *(const bf16x8*)&Vt[(c * 8 + ( g      ^ (c & 7))) * 8]; \
      vf[2 * ct + 1] = *(const bf16x8*)&Vt[(c * 8 + ((4 + g) ^ (c & 7))) * 8]; \
    }                                                                          \
    const int jq2 = ((nn + 2) & 63) * 64;                                      \
    _Pragma("unroll")                                                          \
    for (int jt = 0; jt < 4; ++jt)                                             \
      KFN[jt] = *(const bf16x8*)&Kb[(size_t)(jq2 + jt * 16 + ln) * CKEY + g * 8]; \
    asm volatile("" ::: "memory");  /* K loads stay BEFORE the stage DMAs */   \
    const int jn = (nn * 64 + 128) & (N_PIX - 1);                              \
    bf16_t* ldst = &Vlds[(nn + 2) & 3][wave * 2048];                           \
    glds16(vg0 + jn, ldst);                                                    \
    glds16(vg1 + jn, ldst + 512);                                              \
    glds16(vg2 + jn, ldst + 1024);                                             \
    glds16(vg3 + jn, ldst + 1536);                                             \
    bf16x8 pa0n, pa1n;                                                         \
    const bool live = (nn < 63);                                               \
    if (live) softmax_tile(KFU, qf, ones, accsum, pa0n, pa1n);                 \
    asm volatile("s_waitcnt vmcnt(8)" ::: "memory");                           \
    __builtin_amdgcn_s_barrier();                                              \
    asm volatile("" ::: "memory");                                             \
    __builtin_amdgcn_s_setprio(1);                                             \
    _Pragma("unroll")                                                          \
    for (int ct = 0; ct < 8; ++ct) {                                           \
      acc[ct] = mfma16(vf[2 * ct],     pa0c, acc[ct]);                         \
      acc[ct] = mfma16(vf[2 * ct + 1], pa1c, acc[ct]);                         \
    }                                                                          \
    __builtin_amdgcn_s_setprio(0);                                             \
    if (live) { pa0c = pa0n; pa1c = pa1n; }                                    \
  }

    for (int n2 = 0; n2 < 32; ++n2) {
        PV_ITER(2 * n2,     kfA, kfB);
        PV_ITER(2 * n2 + 1, kfB, kfA);
    }
#undef PV_ITER

    // l_i: accsum rows are all identical = full sum over j for i = ln
    const float s_lane = gamma[0] / accsum[0];

#pragma unroll
    for (int ct = 0; ct < 8; ++ct)
#pragma unroll
        for (int r = 0; r < 4; ++r) {
            const int c = c_base + ct * 16 + g * 4 + r;   // D row = c_local
            const int i = i_base + ln;                    // D col = i
            const size_t idx = ((size_t)b * CFEAT + c) * N_PIX + i;
            out[idx] = s_lane * acc[ct][r] + features[idx];
        }
}

// ---------------------------------------------------------------------------
extern "C" void kernel_launch(void* const* d_in, const int* in_sizes, int n_in,
                              void* d_out, int out_size, void* d_ws, size_t ws_size,
                              hipStream_t stream) {
    const float* features   = (const float*)d_in[0];
    const float* conditions = (const float*)d_in[1];
    const float* Wq  = (const float*)d_in[2];
    const float* bq  = (const float*)d_in[3];
    const float* Wk  = (const float*)d_in[4];
    const float* bk  = (const float*)d_in[5];
    const float* Wv  = (const float*)d_in[6];
    const float* bv  = (const float*)d_in[7];
    const float* gam = (const float*)d_in[8];
    float* out = (float*)d_out;

    // ws (bf16): Qt 1MB | Kt 1MB | V 8MB
    bf16_t* Qt = (bf16_t*)d_ws;
    bf16_t* Kt = Qt + (size_t)NBATCH * N_PIX * CKEY;
    bf16_t* Vw = Kt + (size_t)NBATCH * N_PIX * CKEY;

    proj_kernel<<<dim3(1024, 1, 1), 256, 0, stream>>>(
        Wq, bq, conditions, Wk, bk, features, Wv, bv, Qt, Kt, Vw);
    pv_kernel<<<dim3(2, N_PIX / 64, NBATCH), 256, 0, stream>>>(
        Qt, Kt, Vw, features, gam, out);
}